// Round 1
// baseline (4622.401 us; speedup 1.0000x reference)
//
#include <hip/hip_runtime.h>
#include <hip/hip_bf16.h>

// Problem dims
#define T_DIM 256
#define B_DIM 64
#define I_DIM 512
#define H_DIM 1024
#define U_DIM 8
#define BN_EPS 1e-5f

typedef __bf16 bf16x8 __attribute__((ext_vector_type(8)));
typedef float f32x4 __attribute__((ext_vector_type(4)));
using bf16 = __hip_bfloat16;

// ---------------- conversion / packing kernels ----------------

__global__ void k_f32_to_bf16(const float* __restrict__ in, bf16* __restrict__ out, int n) {
    int i = blockIdx.x * blockDim.x + threadIdx.x;
    int stride = gridDim.x * blockDim.x;
    for (; i < n; i += stride) out[i] = __float2bfloat16(in[i]);
}

// pack [Uz; Uh] into one [2048,1024] bf16 K-major matrix
__global__ void k_pack_uzuh(const float* __restrict__ Uz, const float* __restrict__ Uh,
                            bf16* __restrict__ out) {
    int idx = blockIdx.x * 256 + threadIdx.x;
    int stride = gridDim.x * 256;
    for (; idx < 2 * H_DIM * H_DIM; idx += stride) {
        int n = idx >> 10, k = idx & 1023;
        float v = (n < H_DIM) ? Uz[(size_t)n * H_DIM + k] : Uh[(size_t)(n - H_DIM) * H_DIM + k];
        out[idx] = __float2bfloat16(v);
    }
}

// extract block-diagonal of Wm = Wh_in * mask: wdiag[h*8+u] = Wm[h][h*8+u]
__global__ void k_wdiag(const float* __restrict__ Wh_in, const float* __restrict__ mask,
                        float* __restrict__ wdiag) {
    int idx = blockIdx.x * 256 + threadIdx.x;
    if (idx < H_DIM * U_DIM) {
        int h = idx >> 3;
        size_t col = (size_t)h * (H_DIM * U_DIM) + idx;  // row h, column h*8+u == idx
        wdiag[idx] = Wh_in[col] * mask[col];
    }
}

// ---------------- GEMM: zx = x @ Wzx.T  (raw fp32 into d_out) ----------------
// grid (H/64, T), 256 threads = 4 waves; wave = one 16-row m-tile x 64 cols

__global__ __launch_bounds__(256) void k_gemm_zx(const bf16* __restrict__ xb,
                                                 const bf16* __restrict__ wzx,
                                                 float* __restrict__ raw) {
    int t = blockIdx.y;
    int h0 = blockIdx.x * 64;
    int lane = threadIdx.x & 63;
    int wid = threadIdx.x >> 6;
    int row = lane & 15;
    int kseg = lane >> 4;
    const bf16* xrow = xb + (size_t)(t * B_DIM + wid * 16 + row) * I_DIM + kseg * 8;
    f32x4 acc[4] = {};
    for (int kk = 0; kk < I_DIM; kk += 32) {
        bf16x8 a = *reinterpret_cast<const bf16x8*>(xrow + kk);
#pragma unroll
        for (int nf = 0; nf < 4; ++nf) {
            const bf16* brow = wzx + (size_t)(h0 + nf * 16 + row) * I_DIM + kk + kseg * 8;
            bf16x8 b = *reinterpret_cast<const bf16x8*>(brow);
            acc[nf] = __builtin_amdgcn_mfma_f32_16x16x32_bf16(
                *(const bf16x8*)&a, *(const bf16x8*)&b, acc[nf], 0, 0, 0);
        }
    }
    int bb = wid * 16 + kseg * 4;
#pragma unroll
    for (int nf = 0; nf < 4; ++nf) {
        int h = h0 + nf * 16 + row;
#pragma unroll
        for (int j = 0; j < 4; ++j)
            raw[(size_t)(t * B_DIM + bb + j) * H_DIM + h] = acc[nf][j];
    }
}

// ---------------- GEMM: s = relu(x @ Whx.T + b_unit) @ Wm.T (raw fp32 into d_out) ----------------
// grid (H/16, T): each block does a [64 x 128] u-column tile -> reduced to [64 x 16] h outputs

__global__ __launch_bounds__(256) void k_gemm_s(const bf16* __restrict__ xb,
                                                const bf16* __restrict__ whx,
                                                const float* __restrict__ b_unit,
                                                const float* __restrict__ wdiag,
                                                float* __restrict__ raw) {
    int t = blockIdx.y;
    int h0 = blockIdx.x * 16;
    int u0 = h0 * U_DIM;  // base row of Whx (128 rows per block)
    int lane = threadIdx.x & 63;
    int wid = threadIdx.x >> 6;
    int row = lane & 15;
    int kseg = lane >> 4;
    const bf16* xrow = xb + (size_t)(t * B_DIM + wid * 16 + row) * I_DIM + kseg * 8;
    f32x4 acc[8] = {};
    for (int kk = 0; kk < I_DIM; kk += 32) {
        bf16x8 a = *reinterpret_cast<const bf16x8*>(xrow + kk);
#pragma unroll
        for (int nf = 0; nf < 8; ++nf) {
            const bf16* brow = whx + (size_t)(u0 + nf * 16 + row) * I_DIM + kk + kseg * 8;
            bf16x8 b = *reinterpret_cast<const bf16x8*>(brow);
            acc[nf] = __builtin_amdgcn_mfma_f32_16x16x32_bf16(a, b, acc[nf], 0, 0, 0);
        }
    }
    // epilogue: v = relu(acc + b_unit[ucol]) * wdiag[ucol]; sum groups of 8 u-lanes -> one h
    int bb = wid * 16 + kseg * 4;
    int uloc = row & 7;
#pragma unroll
    for (int nf = 0; nf < 8; ++nf) {
        int ucol = u0 + nf * 16 + row;     // global column = h*8+u
        float wd = wdiag[ucol];
        float bu = b_unit[ucol];
        int h = h0 + nf * 2 + (row >> 3);
#pragma unroll
        for (int j = 0; j < 4; ++j) {
            float v = fmaxf(acc[nf][j] + bu, 0.f) * wd;
            v += __shfl_xor(v, 1);
            v += __shfl_xor(v, 2);
            v += __shfl_xor(v, 4);
            if (uloc == 0) raw[(size_t)(t * B_DIM + bb + j) * H_DIM + h] = v;
        }
    }
}

// ---------------- BN over batch: out = (raw - mu)*rsqrt(var+eps)*g + b  (bf16) ----------------
// one block per t; stats over the 64 batch rows

__global__ __launch_bounds__(256) void k_bn(const float* __restrict__ raw,
                                            const float* __restrict__ g,
                                            const float* __restrict__ bta,
                                            bf16* __restrict__ out) {
    int t = blockIdx.x;
    const float* base = raw + (size_t)t * B_DIM * H_DIM;
    bf16* ob = out + (size_t)t * B_DIM * H_DIM;
    for (int h = threadIdx.x; h < H_DIM; h += 256) {
        float s = 0.f, s2 = 0.f;
        for (int b = 0; b < B_DIM; ++b) {
            float v = base[(size_t)b * H_DIM + h];
            s += v;
            s2 += v * v;
        }
        float mu = s * (1.f / B_DIM);
        float var = s2 * (1.f / B_DIM) - mu * mu;
        float sc = rsqrtf(var + BN_EPS) * g[h];
        float sh = bta[h] - mu * sc;
        for (int b = 0; b < B_DIM; ++b) {
            float v = base[(size_t)b * H_DIM + h];
            ob[(size_t)b * H_DIM + h] = __float2bfloat16(v * sc + sh);
        }
    }
}

// ---------------- recurrent step ----------------
// grid (H/16): per block [64 x 16] tile of both Uz and Uh GEMMs + gating

__global__ __launch_bounds__(256) void k_step(const bf16* __restrict__ hprev_b,
                                              const float* __restrict__ hprev_f,
                                              const bf16* __restrict__ uzuh,
                                              const bf16* __restrict__ bnz_t,
                                              const bf16* __restrict__ bnh_t,
                                              float* __restrict__ hnext_f,
                                              bf16* __restrict__ hnext_b,
                                              float* __restrict__ out_t) {
    int h0 = blockIdx.x * 16;
    int lane = threadIdx.x & 63;
    int wid = threadIdx.x >> 6;
    int row = lane & 15;
    int kseg = lane >> 4;
    const bf16* arow = hprev_b + (size_t)(wid * 16 + row) * H_DIM + kseg * 8;
    const bf16* bzr = uzuh + (size_t)(h0 + row) * H_DIM + kseg * 8;
    const bf16* bhr = uzuh + (size_t)(H_DIM + h0 + row) * H_DIM + kseg * 8;
    f32x4 accZ = {}, accH = {};
    for (int kk = 0; kk < H_DIM; kk += 32) {
        bf16x8 a = *reinterpret_cast<const bf16x8*>(arow + kk);
        bf16x8 b1 = *reinterpret_cast<const bf16x8*>(bzr + kk);
        bf16x8 b2 = *reinterpret_cast<const bf16x8*>(bhr + kk);
        accZ = __builtin_amdgcn_mfma_f32_16x16x32_bf16(a, b1, accZ, 0, 0, 0);
        accH = __builtin_amdgcn_mfma_f32_16x16x32_bf16(a, b2, accH, 0, 0, 0);
    }
    int bb = wid * 16 + kseg * 4;
    int h = h0 + row;
#pragma unroll
    for (int j = 0; j < 4; ++j) {
        size_t idx = (size_t)(bb + j) * H_DIM + h;
        float z = 1.f / (1.f + expf(-(__bfloat162float(bnz_t[idx]) + accZ[j])));
        float hu = fmaxf(__bfloat162float(bnh_t[idx]) + accH[j], 0.f);
        float hp = hprev_f[idx];
        float hn = z * hp + (1.f - z) * hu;
        hnext_f[idx] = hn;
        hnext_b[idx] = __float2bfloat16(hn);
        out_t[idx] = hn;
    }
}

__global__ void k_copy_f32(const float* __restrict__ in, float* __restrict__ out, int n) {
    int i = blockIdx.x * blockDim.x + threadIdx.x;
    if (i < n) out[i] = in[i];
}

// ---------------- workspace layout (bytes) ----------------
#define OFF_XB    ((size_t)0)                     // 16 MB  bf16 x
#define OFF_WZX   ((size_t)16777216)              // 1 MB
#define OFF_WHX   ((size_t)17825792)              // 8 MB
#define OFF_UZUH  ((size_t)26214400)              // 4 MB
#define OFF_WDIAG ((size_t)30408704)              // 32 KB
#define OFF_BNZ   ((size_t)30441472)              // 32 MB
#define OFF_BNH   ((size_t)63995904)              // 32 MB
#define OFF_HF0   ((size_t)97550336)              // 256 KB
#define OFF_HF1   ((size_t)97812480)              // 256 KB
#define OFF_HB0   ((size_t)98074624)              // 128 KB
#define OFF_HB1   ((size_t)98205696)              // 128 KB

extern "C" void kernel_launch(void* const* d_in, const int* in_sizes, int n_in,
                              void* d_out, int out_size, void* d_ws, size_t ws_size,
                              hipStream_t stream) {
    const float* x      = (const float*)d_in[0];
    const float* Wzx    = (const float*)d_in[1];
    const float* Whx    = (const float*)d_in[2];
    const float* Uz     = (const float*)d_in[3];
    const float* Uh     = (const float*)d_in[4];
    const float* b_unit = (const float*)d_in[5];
    const float* Wh_in  = (const float*)d_in[6];
    const float* gz     = (const float*)d_in[7];
    const float* bz     = (const float*)d_in[8];
    const float* gh     = (const float*)d_in[9];
    const float* bh     = (const float*)d_in[10];
    const float* mask   = (const float*)d_in[11];

    char* ws = (char*)d_ws;
    bf16*  xb    = (bf16*)(ws + OFF_XB);
    bf16*  wzx_b = (bf16*)(ws + OFF_WZX);
    bf16*  whx_b = (bf16*)(ws + OFF_WHX);
    bf16*  uzuh  = (bf16*)(ws + OFF_UZUH);
    float* wdiag = (float*)(ws + OFF_WDIAG);
    bf16*  bnz   = (bf16*)(ws + OFF_BNZ);
    bf16*  bnh   = (bf16*)(ws + OFF_BNH);
    float* hf[2] = {(float*)(ws + OFF_HF0), (float*)(ws + OFF_HF1)};
    bf16*  hb[2] = {(bf16*)(ws + OFF_HB0), (bf16*)(ws + OFF_HB1)};

    float* out = (float*)d_out;
    float* raw = out;  // reuse d_out as fp32 scratch for pre-BN GEMM outputs

    // 1. convert inputs to bf16
    {
        int n = T_DIM * B_DIM * I_DIM;
        k_f32_to_bf16<<<4096, 256, 0, stream>>>(x, xb, n);
        k_f32_to_bf16<<<2048, 256, 0, stream>>>(Wzx, wzx_b, H_DIM * I_DIM);
        k_f32_to_bf16<<<4096, 256, 0, stream>>>(Whx, whx_b, U_DIM * H_DIM * I_DIM);
        k_pack_uzuh<<<4096, 256, 0, stream>>>(Uz, Uh, uzuh);
        k_wdiag<<<(H_DIM * U_DIM + 255) / 256, 256, 0, stream>>>(Wh_in, mask, wdiag);
    }

    // 2. zx GEMM -> raw (fp32 in d_out), then BN -> bnz (bf16)
    {
        dim3 grid(H_DIM / 64, T_DIM);
        k_gemm_zx<<<grid, 256, 0, stream>>>(xb, wzx_b, raw);
        k_bn<<<T_DIM, 256, 0, stream>>>(raw, gz, bz, bnz);
    }

    // 3. s GEMM (fused relu + block-diag reduce) -> raw, then BN -> bnh
    {
        dim3 grid(H_DIM / 16, T_DIM);
        k_gemm_s<<<grid, 256, 0, stream>>>(xb, whx_b, b_unit, wdiag, raw);
        k_bn<<<T_DIM, 256, 0, stream>>>(raw, gh, bh, bnh);
    }

    // 4. init h = 0
    hipMemsetAsync(hf[0], 0, (size_t)B_DIM * H_DIM * sizeof(float), stream);
    hipMemsetAsync(hb[0], 0, (size_t)B_DIM * H_DIM * sizeof(bf16), stream);

    // 5. recurrent scan: 256 sequential step kernels (ping-pong h buffers)
    int cur = 0;
    for (int t = 0; t < T_DIM; ++t) {
        int nxt = cur ^ 1;
        k_step<<<H_DIM / 16, 256, 0, stream>>>(
            hb[cur], hf[cur], uzuh,
            bnz + (size_t)t * B_DIM * H_DIM,
            bnh + (size_t)t * B_DIM * H_DIM,
            hf[nxt], hb[nxt],
            out + (size_t)t * B_DIM * H_DIM);
        cur = nxt;
    }

    // 6. h_final = last h -> tail of d_out
    k_copy_f32<<<(B_DIM * H_DIM + 255) / 256, 256, 0, stream>>>(
        hf[cur], out + (size_t)T_DIM * B_DIM * H_DIM, B_DIM * H_DIM);
}

// Round 2
// 3824.920 us; speedup vs baseline: 1.2085x; 1.2085x over previous
//
#include <hip/hip_runtime.h>
#include <hip/hip_bf16.h>

// Problem dims
#define T_DIM 256
#define B_DIM 64
#define I_DIM 512
#define H_DIM 1024
#define U_DIM 8
#define BN_EPS 1e-5f
#define NBLK 64   // blocks in persistent scan kernel

typedef __bf16 bf16x8 __attribute__((ext_vector_type(8)));
typedef float f32x4 __attribute__((ext_vector_type(4)));
using bf16 = __hip_bfloat16;

// ---------------- conversion / packing kernels ----------------

__global__ void k_f32_to_bf16(const float* __restrict__ in, bf16* __restrict__ out, int n) {
    int i = blockIdx.x * blockDim.x + threadIdx.x;
    int stride = gridDim.x * blockDim.x;
    for (; i < n; i += stride) out[i] = __float2bfloat16(in[i]);
}

// pack [Uz; Uh] into one [2048,1024] bf16 K-major matrix
__global__ void k_pack_uzuh(const float* __restrict__ Uz, const float* __restrict__ Uh,
                            bf16* __restrict__ out) {
    int idx = blockIdx.x * 256 + threadIdx.x;
    int stride = gridDim.x * 256;
    for (; idx < 2 * H_DIM * H_DIM; idx += stride) {
        int n = idx >> 10, k = idx & 1023;
        float v = (n < H_DIM) ? Uz[(size_t)n * H_DIM + k] : Uh[(size_t)(n - H_DIM) * H_DIM + k];
        out[idx] = __float2bfloat16(v);
    }
}

// extract block-diagonal of Wm = Wh_in * mask: wdiag[h*8+u] = Wm[h][h*8+u]
__global__ void k_wdiag(const float* __restrict__ Wh_in, const float* __restrict__ mask,
                        float* __restrict__ wdiag) {
    int idx = blockIdx.x * 256 + threadIdx.x;
    if (idx < H_DIM * U_DIM) {
        int h = idx >> 3;
        size_t col = (size_t)h * (H_DIM * U_DIM) + idx;  // row h, column h*8+u == idx
        wdiag[idx] = Wh_in[col] * mask[col];
    }
}

// ---------------- GEMM: zx = x @ Wzx.T  (raw fp32 into d_out) ----------------
// grid (H/64, T), 256 threads = 4 waves; wave = one 16-row m-tile x 64 cols

__global__ __launch_bounds__(256) void k_gemm_zx(const bf16* __restrict__ xb,
                                                 const bf16* __restrict__ wzx,
                                                 float* __restrict__ raw) {
    int t = blockIdx.y;
    int h0 = blockIdx.x * 64;
    int lane = threadIdx.x & 63;
    int wid = threadIdx.x >> 6;
    int row = lane & 15;
    int kseg = lane >> 4;
    const bf16* xrow = xb + (size_t)(t * B_DIM + wid * 16 + row) * I_DIM + kseg * 8;
    f32x4 acc[4] = {};
    for (int kk = 0; kk < I_DIM; kk += 32) {
        bf16x8 a = *reinterpret_cast<const bf16x8*>(xrow + kk);
#pragma unroll
        for (int nf = 0; nf < 4; ++nf) {
            const bf16* brow = wzx + (size_t)(h0 + nf * 16 + row) * I_DIM + kk + kseg * 8;
            bf16x8 b = *reinterpret_cast<const bf16x8*>(brow);
            acc[nf] = __builtin_amdgcn_mfma_f32_16x16x32_bf16(a, b, acc[nf], 0, 0, 0);
        }
    }
    int bb = wid * 16 + kseg * 4;
#pragma unroll
    for (int nf = 0; nf < 4; ++nf) {
        int h = h0 + nf * 16 + row;
#pragma unroll
        for (int j = 0; j < 4; ++j)
            raw[(size_t)(t * B_DIM + bb + j) * H_DIM + h] = acc[nf][j];
    }
}

// ---------------- GEMM: s = relu(x @ Whx.T + b_unit) @ Wm.T (raw fp32 into d_out) ----------------
// grid (H/16, T): each block does a [64 x 128] u-column tile -> reduced to [64 x 16] h outputs

__global__ __launch_bounds__(256) void k_gemm_s(const bf16* __restrict__ xb,
                                                const bf16* __restrict__ whx,
                                                const float* __restrict__ b_unit,
                                                const float* __restrict__ wdiag,
                                                float* __restrict__ raw) {
    int t = blockIdx.y;
    int h0 = blockIdx.x * 16;
    int u0 = h0 * U_DIM;  // base row of Whx (128 rows per block)
    int lane = threadIdx.x & 63;
    int wid = threadIdx.x >> 6;
    int row = lane & 15;
    int kseg = lane >> 4;
    const bf16* xrow = xb + (size_t)(t * B_DIM + wid * 16 + row) * I_DIM + kseg * 8;
    f32x4 acc[8] = {};
    for (int kk = 0; kk < I_DIM; kk += 32) {
        bf16x8 a = *reinterpret_cast<const bf16x8*>(xrow + kk);
#pragma unroll
        for (int nf = 0; nf < 8; ++nf) {
            const bf16* brow = whx + (size_t)(u0 + nf * 16 + row) * I_DIM + kk + kseg * 8;
            bf16x8 b = *reinterpret_cast<const bf16x8*>(brow);
            acc[nf] = __builtin_amdgcn_mfma_f32_16x16x32_bf16(a, b, acc[nf], 0, 0, 0);
        }
    }
    // epilogue: v = relu(acc + b_unit[ucol]) * wdiag[ucol]; sum groups of 8 u-lanes -> one h
    int bb = wid * 16 + kseg * 4;
    int uloc = row & 7;
#pragma unroll
    for (int nf = 0; nf < 8; ++nf) {
        int ucol = u0 + nf * 16 + row;     // global column = h*8+u
        float wd = wdiag[ucol];
        float bu = b_unit[ucol];
        int h = h0 + nf * 2 + (row >> 3);
#pragma unroll
        for (int j = 0; j < 4; ++j) {
            float v = fmaxf(acc[nf][j] + bu, 0.f) * wd;
            v += __shfl_xor(v, 1);
            v += __shfl_xor(v, 2);
            v += __shfl_xor(v, 4);
            if (uloc == 0) raw[(size_t)(t * B_DIM + bb + j) * H_DIM + h] = v;
        }
    }
}

// ---------------- BN over batch: out = (raw - mu)*rsqrt(var+eps)*g + b  (bf16) ----------------

__global__ __launch_bounds__(256) void k_bn(const float* __restrict__ raw,
                                            const float* __restrict__ g,
                                            const float* __restrict__ bta,
                                            bf16* __restrict__ out) {
    int t = blockIdx.x;
    const float* base = raw + (size_t)t * B_DIM * H_DIM;
    bf16* ob = out + (size_t)t * B_DIM * H_DIM;
    for (int h = threadIdx.x; h < H_DIM; h += 256) {
        float s = 0.f, s2 = 0.f;
        for (int b = 0; b < B_DIM; ++b) {
            float v = base[(size_t)b * H_DIM + h];
            s += v;
            s2 += v * v;
        }
        float mu = s * (1.f / B_DIM);
        float var = s2 * (1.f / B_DIM) - mu * mu;
        float sc = rsqrtf(var + BN_EPS) * g[h];
        float sh = bta[h] - mu * sc;
        for (int b = 0; b < B_DIM; ++b) {
            float v = base[(size_t)b * H_DIM + h];
            ob[(size_t)b * H_DIM + h] = __float2bfloat16(v * sc + sh);
        }
    }
}

// ---------------- persistent scan kernel ----------------
// 64 blocks x 512 threads (8 waves). Block owns 16 h-columns. Wave w: mq=w&3
// (16 batch rows), kq=w>>2 (k-half of the 1024-wide reduction). Uz/Uh fragments
// for this block's columns live in REGISTERS across all 256 steps (128 VGPRs).
// Per step: MFMA partials -> LDS k-reduce -> gating on kq==0 waves (h carried
// in fp32 registers) -> grid barrier (device-scope acq/rel atomics).

__global__ __launch_bounds__(512, 2) void k_scan(const bf16* __restrict__ uzuh,
                                                 const bf16* __restrict__ bnz,
                                                 const bf16* __restrict__ bnh,
                                                 bf16* __restrict__ hb0,
                                                 bf16* __restrict__ hb1,
                                                 float* __restrict__ out,
                                                 unsigned* __restrict__ bar) {
    int tid = threadIdx.x;
    int lane = tid & 63, w = tid >> 6;
    int mq = w & 3, kq = w >> 2;
    int r15 = lane & 15, kseg = lane >> 4;
    int h0 = blockIdx.x * 16;
    int hcol = h0 + r15;

    // load this wave's permanent B fragments (Uz & Uh rows = this block's h cols)
    bf16x8 bZ[16], bH[16];
    {
        const bf16* bzbase = uzuh + (size_t)hcol * H_DIM + kq * 512 + kseg * 8;
        const bf16* bhbase = bzbase + (size_t)H_DIM * H_DIM;
#pragma unroll
        for (int i = 0; i < 16; ++i) {
            bZ[i] = *reinterpret_cast<const bf16x8*>(bzbase + i * 32);
            bH[i] = *reinterpret_cast<const bf16x8*>(bhbase + i * 32);
        }
    }

    __shared__ float red[2][4][64][4];  // [tile Z/H][mq][lane][j] partials from kq==1

    f32x4 hreg = {};                    // fp32 h carried in regs (kq==0 waves)
    int arow = mq * 16 + r15;           // batch row this lane reads for A
    int bb = mq * 16 + kseg * 4;        // batch row base of C fragment
    unsigned target = 0;

    for (int t = 0; t < T_DIM; ++t) {
        const bf16* hbc = (t & 1) ? hb1 : hb0;
        bf16* hbn = (t & 1) ? hb0 : hb1;

        // prefetch BN'd input-projection values for this step (independent of h)
        float bzv[4], bhv[4];
        if (kq == 0) {
            const bf16* pz = bnz + (size_t)t * (B_DIM * H_DIM) + (size_t)bb * H_DIM + hcol;
            const bf16* ph = bnh + (size_t)t * (B_DIM * H_DIM) + (size_t)bb * H_DIM + hcol;
#pragma unroll
            for (int j = 0; j < 4; ++j) {
                bzv[j] = __bfloat162float(pz[j * H_DIM]);
                bhv[j] = __bfloat162float(ph[j * H_DIM]);
            }
        }

        // k-half GEMM: acc += h_prev[mq rows, kq half] x {Uz,Uh}
        f32x4 accZ = {}, accH = {};
        const bf16* ap = hbc + (size_t)arow * H_DIM + kq * 512 + kseg * 8;
#pragma unroll
        for (int i = 0; i < 16; ++i) {
            bf16x8 a = *reinterpret_cast<const bf16x8*>(ap + i * 32);
            accZ = __builtin_amdgcn_mfma_f32_16x16x32_bf16(a, bZ[i], accZ, 0, 0, 0);
            accH = __builtin_amdgcn_mfma_f32_16x16x32_bf16(a, bH[i], accH, 0, 0, 0);
        }

        __syncthreads();  // previous iteration's reduce reads are done (LDS WAR)
        if (kq == 1) {
            *reinterpret_cast<f32x4*>(&red[0][mq][lane][0]) = accZ;
            *reinterpret_cast<f32x4*>(&red[1][mq][lane][0]) = accH;
        }
        __syncthreads();

        if (kq == 0) {
            accZ += *reinterpret_cast<const f32x4*>(&red[0][mq][lane][0]);
            accH += *reinterpret_cast<const f32x4*>(&red[1][mq][lane][0]);
            float* op = out + (size_t)t * (B_DIM * H_DIM);
#pragma unroll
            for (int j = 0; j < 4; ++j) {
                float z = 1.f / (1.f + expf(-(bzv[j] + accZ[j])));
                float hu = fmaxf(bhv[j] + accH[j], 0.f);
                float hn = z * hreg[j] + (1.f - z) * hu;
                hreg[j] = hn;
                size_t idx = (size_t)(bb + j) * H_DIM + hcol;
                op[idx] = hn;
                hbn[idx] = __float2bfloat16(hn);
                if (t == T_DIM - 1)
                    out[(size_t)T_DIM * (B_DIM * H_DIM) + idx] = hn;  // h_final tail
            }
        }

        if (t < T_DIM - 1) {
            __syncthreads();  // drains each wave's vmem before s_barrier
            target += NBLK;
            if (tid == 0) {
                __hip_atomic_fetch_add(bar, 1u, __ATOMIC_RELEASE, __HIP_MEMORY_SCOPE_AGENT);
                while (__hip_atomic_load(bar, __ATOMIC_ACQUIRE, __HIP_MEMORY_SCOPE_AGENT) < target)
                    __builtin_amdgcn_s_sleep(1);
            }
            __syncthreads();
        }
    }
}

// ---------------- workspace layout (bytes) ----------------
#define OFF_XB    ((size_t)0)                     // 16 MB  bf16 x
#define OFF_WZX   ((size_t)16777216)              // 1 MB
#define OFF_WHX   ((size_t)17825792)              // 8 MB
#define OFF_UZUH  ((size_t)26214400)              // 4 MB
#define OFF_WDIAG ((size_t)30408704)              // 32 KB
#define OFF_BNZ   ((size_t)30441472)              // 32 MB
#define OFF_BNH   ((size_t)63995904)              // 32 MB
#define OFF_BAR   ((size_t)97550336)              // 128 B (old hf0 slot)
#define OFF_HB0   ((size_t)98074624)              // 128 KB
#define OFF_HB1   ((size_t)98205696)              // 128 KB

extern "C" void kernel_launch(void* const* d_in, const int* in_sizes, int n_in,
                              void* d_out, int out_size, void* d_ws, size_t ws_size,
                              hipStream_t stream) {
    const float* x      = (const float*)d_in[0];
    const float* Wzx    = (const float*)d_in[1];
    const float* Whx    = (const float*)d_in[2];
    const float* Uz     = (const float*)d_in[3];
    const float* Uh     = (const float*)d_in[4];
    const float* b_unit = (const float*)d_in[5];
    const float* Wh_in  = (const float*)d_in[6];
    const float* gz     = (const float*)d_in[7];
    const float* bz     = (const float*)d_in[8];
    const float* gh     = (const float*)d_in[9];
    const float* bh     = (const float*)d_in[10];
    const float* mask   = (const float*)d_in[11];

    char* ws = (char*)d_ws;
    bf16*     xb    = (bf16*)(ws + OFF_XB);
    bf16*     wzx_b = (bf16*)(ws + OFF_WZX);
    bf16*     whx_b = (bf16*)(ws + OFF_WHX);
    bf16*     uzuh  = (bf16*)(ws + OFF_UZUH);
    float*    wdiag = (float*)(ws + OFF_WDIAG);
    bf16*     bnz   = (bf16*)(ws + OFF_BNZ);
    bf16*     bnh   = (bf16*)(ws + OFF_BNH);
    unsigned* bar   = (unsigned*)(ws + OFF_BAR);
    bf16*     hb0   = (bf16*)(ws + OFF_HB0);
    bf16*     hb1   = (bf16*)(ws + OFF_HB1);

    float* out = (float*)d_out;
    float* raw = out;  // reuse d_out as fp32 scratch for pre-BN GEMM outputs

    // 1. convert inputs to bf16
    {
        int n = T_DIM * B_DIM * I_DIM;
        k_f32_to_bf16<<<4096, 256, 0, stream>>>(x, xb, n);
        k_f32_to_bf16<<<2048, 256, 0, stream>>>(Wzx, wzx_b, H_DIM * I_DIM);
        k_f32_to_bf16<<<4096, 256, 0, stream>>>(Whx, whx_b, U_DIM * H_DIM * I_DIM);
        k_pack_uzuh<<<4096, 256, 0, stream>>>(Uz, Uh, uzuh);
        k_wdiag<<<(H_DIM * U_DIM + 255) / 256, 256, 0, stream>>>(Wh_in, mask, wdiag);
    }

    // 2. zx GEMM -> raw (fp32 in d_out), then BN -> bnz (bf16)
    {
        dim3 grid(H_DIM / 64, T_DIM);
        k_gemm_zx<<<grid, 256, 0, stream>>>(xb, wzx_b, raw);
        k_bn<<<T_DIM, 256, 0, stream>>>(raw, gz, bz, bnz);
    }

    // 3. s GEMM (fused relu + block-diag reduce) -> raw, then BN -> bnh
    {
        dim3 grid(H_DIM / 16, T_DIM);
        k_gemm_s<<<grid, 256, 0, stream>>>(xb, whx_b, b_unit, wdiag, raw);
        k_bn<<<T_DIM, 256, 0, stream>>>(raw, gh, bh, bnh);
    }

    // 4. init h = 0 and barrier = 0
    hipMemsetAsync(hb0, 0, (size_t)B_DIM * H_DIM * sizeof(bf16), stream);
    hipMemsetAsync(bar, 0, 128, stream);

    // 5. persistent scan: one kernel, grid barrier per step
    k_scan<<<NBLK, 512, 0, stream>>>(uzuh, bnz, bnh, hb0, hb1, out, bar);
}

// Round 3
// 3031.454 us; speedup vs baseline: 1.5248x; 1.2617x over previous
//
#include <hip/hip_runtime.h>
#include <hip/hip_bf16.h>

// Problem dims
#define T_DIM 256
#define B_DIM 64
#define I_DIM 512
#define H_DIM 1024
#define U_DIM 8
#define BN_EPS 1e-5f
#define NBLK 64   // blocks in persistent scan kernel

typedef __bf16 bf16x8 __attribute__((ext_vector_type(8)));
typedef float f32x4 __attribute__((ext_vector_type(4)));
typedef unsigned short u16;
typedef u16 u16x4 __attribute__((ext_vector_type(4)));
using bf16 = __hip_bfloat16;

// ---------------- conversion / packing kernels (vectorized) ----------------

__global__ void k_cvt4(const float* __restrict__ in, u16* __restrict__ out, int n4) {
    int i = blockIdx.x * blockDim.x + threadIdx.x;
    int stride = gridDim.x * blockDim.x;
    for (; i < n4; i += stride) {
        f32x4 v = *reinterpret_cast<const f32x4*>(in + (size_t)i * 4);
        u16x4 o;
#pragma unroll
        for (int j = 0; j < 4; ++j)
            o[j] = __bfloat16_as_ushort(__float2bfloat16(v[j]));
        *reinterpret_cast<u16x4*>(out + (size_t)i * 4) = o;
    }
}

// pack [Uz; Uh] into one [2048,1024] bf16 K-major matrix (4-elem chunks)
__global__ void k_pack_uzuh(const float* __restrict__ Uz, const float* __restrict__ Uh,
                            u16* __restrict__ out) {
    int i = blockIdx.x * 256 + threadIdx.x;
    int stride = gridDim.x * 256;
    int n4 = 2 * H_DIM * H_DIM / 4;
    for (; i < n4; i += stride) {
        int c = i * 4;
        int n = c >> 10, k = c & 1023;
        const float* src = (n < H_DIM) ? (Uz + (size_t)n * H_DIM + k)
                                       : (Uh + (size_t)(n - H_DIM) * H_DIM + k);
        f32x4 v = *reinterpret_cast<const f32x4*>(src);
        u16x4 o;
#pragma unroll
        for (int j = 0; j < 4; ++j)
            o[j] = __bfloat16_as_ushort(__float2bfloat16(v[j]));
        *reinterpret_cast<u16x4*>(out + c) = o;
    }
}

// extract block-diagonal of Wm = Wh_in * mask: wdiag[h*8+u] = Wm[h][h*8+u]
__global__ void k_wdiag(const float* __restrict__ Wh_in, const float* __restrict__ mask,
                        float* __restrict__ wdiag) {
    int idx = blockIdx.x * 256 + threadIdx.x;
    if (idx < H_DIM * U_DIM) {
        int h = idx >> 3;
        size_t col = (size_t)h * (H_DIM * U_DIM) + idx;
        wdiag[idx] = Wh_in[col] * mask[col];
    }
}

// ---------------- GEMM+BN fused: bnz = BN(x @ Wzx.T) (bf16) ----------------
// grid (H/64, T), 256 threads = 4 waves; block holds the FULL batch for its
// 64 columns -> batch stats via shfl+LDS reduce, write bf16 directly.

__global__ __launch_bounds__(256) void k_gemm_zx(const bf16* __restrict__ xb,
                                                 const bf16* __restrict__ wzx,
                                                 const float* __restrict__ g,
                                                 const float* __restrict__ bta,
                                                 bf16* __restrict__ bnz) {
    int t = blockIdx.y;
    int h0 = blockIdx.x * 64;
    int lane = threadIdx.x & 63;
    int wid = threadIdx.x >> 6;
    int r15 = lane & 15;
    int kseg = lane >> 4;
    const bf16* xrow = xb + (size_t)(t * B_DIM + wid * 16 + r15) * I_DIM + kseg * 8;
    f32x4 acc[4] = {};
    for (int kk = 0; kk < I_DIM; kk += 32) {
        bf16x8 a = *reinterpret_cast<const bf16x8*>(xrow + kk);
#pragma unroll
        for (int nf = 0; nf < 4; ++nf) {
            const bf16* brow = wzx + (size_t)(h0 + nf * 16 + r15) * I_DIM + kk + kseg * 8;
            bf16x8 b = *reinterpret_cast<const bf16x8*>(brow);
            acc[nf] = __builtin_amdgcn_mfma_f32_16x16x32_bf16(a, b, acc[nf], 0, 0, 0);
        }
    }
    // ---- fused BN ----
    __shared__ float sB[2][4][64];   // [s|s2][wid][col]
#pragma unroll
    for (int nf = 0; nf < 4; ++nf) {
        float s = acc[nf][0] + acc[nf][1] + acc[nf][2] + acc[nf][3];
        float s2 = acc[nf][0] * acc[nf][0] + acc[nf][1] * acc[nf][1] +
                   acc[nf][2] * acc[nf][2] + acc[nf][3] * acc[nf][3];
        s += __shfl_xor(s, 16);  s += __shfl_xor(s, 32);
        s2 += __shfl_xor(s2, 16); s2 += __shfl_xor(s2, 32);
        if (lane < 16) { sB[0][wid][nf * 16 + r15] = s; sB[1][wid][nf * 16 + r15] = s2; }
    }
    __syncthreads();
    int bb = wid * 16 + kseg * 4;
#pragma unroll
    for (int nf = 0; nf < 4; ++nf) {
        int c = nf * 16 + r15;
        float s = sB[0][0][c] + sB[0][1][c] + sB[0][2][c] + sB[0][3][c];
        float s2 = sB[1][0][c] + sB[1][1][c] + sB[1][2][c] + sB[1][3][c];
        float mu = s * (1.f / B_DIM);
        float var = s2 * (1.f / B_DIM) - mu * mu;
        int h = h0 + c;
        float sc = rsqrtf(var + BN_EPS) * g[h];
        float sh = bta[h] - mu * sc;
#pragma unroll
        for (int j = 0; j < 4; ++j)
            bnz[(size_t)(t * B_DIM + bb + j) * H_DIM + h] =
                __float2bfloat16(acc[nf][j] * sc + sh);
    }
}

// ---- GEMM+BN fused: bnh = BN(relu(x @ Whx.T + b_unit) @ Wm.T) (bf16) ----
// grid (H/16, T): block = [64 x 128] u-tile -> u-group reduce -> 16 h cols -> BN

__global__ __launch_bounds__(256) void k_gemm_s(const bf16* __restrict__ xb,
                                                const bf16* __restrict__ whx,
                                                const float* __restrict__ b_unit,
                                                const float* __restrict__ wdiag,
                                                const float* __restrict__ g,
                                                const float* __restrict__ bta,
                                                bf16* __restrict__ bnh) {
    int t = blockIdx.y;
    int h0 = blockIdx.x * 16;
    int u0 = h0 * U_DIM;
    int lane = threadIdx.x & 63;
    int wid = threadIdx.x >> 6;
    int r15 = lane & 15;
    int kseg = lane >> 4;
    const bf16* xrow = xb + (size_t)(t * B_DIM + wid * 16 + r15) * I_DIM + kseg * 8;
    f32x4 acc[8] = {};
    for (int kk = 0; kk < I_DIM; kk += 32) {
        bf16x8 a = *reinterpret_cast<const bf16x8*>(xrow + kk);
#pragma unroll
        for (int nf = 0; nf < 8; ++nf) {
            const bf16* brow = whx + (size_t)(u0 + nf * 16 + r15) * I_DIM + kk + kseg * 8;
            bf16x8 b = *reinterpret_cast<const bf16x8*>(brow);
            acc[nf] = __builtin_amdgcn_mfma_f32_16x16x32_bf16(a, b, acc[nf], 0, 0, 0);
        }
    }
    // relu+bias+scale, reduce u-groups of 8 lanes; all lanes end with group sum
    int uloc = r15 & 7;
#pragma unroll
    for (int nf = 0; nf < 8; ++nf) {
        int ucol = u0 + nf * 16 + r15;
        float wd = wdiag[ucol];
        float bu = b_unit[ucol];
#pragma unroll
        for (int j = 0; j < 4; ++j) {
            float v = fmaxf(acc[nf][j] + bu, 0.f) * wd;
            v += __shfl_xor(v, 1);
            v += __shfl_xor(v, 2);
            v += __shfl_xor(v, 4);
            acc[nf][j] = v;   // same value across the 8 u-lanes
        }
    }
    // ---- fused BN over batch for the 16 h columns ----
    __shared__ float sS[2][4][16];
#pragma unroll
    for (int nf = 0; nf < 8; ++nf) {
        float s = 0.f, s2 = 0.f;
        if (uloc == 0) {
#pragma unroll
            for (int j = 0; j < 4; ++j) { s += acc[nf][j]; s2 += acc[nf][j] * acc[nf][j]; }
        }
        s += __shfl_xor(s, 16);  s += __shfl_xor(s, 32);
        s2 += __shfl_xor(s2, 16); s2 += __shfl_xor(s2, 32);
        if (lane == 0 || lane == 8) {
            int c = nf * 2 + (r15 >> 3);
            sS[0][wid][c] = s;
            sS[1][wid][c] = s2;
        }
    }
    __syncthreads();
    int bb = wid * 16 + kseg * 4;
#pragma unroll
    for (int nf = 0; nf < 8; ++nf) {
        int c = nf * 2 + (r15 >> 3);
        float s = sS[0][0][c] + sS[0][1][c] + sS[0][2][c] + sS[0][3][c];
        float s2 = sS[1][0][c] + sS[1][1][c] + sS[1][2][c] + sS[1][3][c];
        float mu = s * (1.f / B_DIM);
        float var = s2 * (1.f / B_DIM) - mu * mu;
        int h = h0 + c;
        float sc = rsqrtf(var + BN_EPS) * g[h];
        float sh = bta[h] - mu * sc;
        if (uloc == 0) {
#pragma unroll
            for (int j = 0; j < 4; ++j)
                bnh[(size_t)(t * B_DIM + bb + j) * H_DIM + h] =
                    __float2bfloat16(acc[nf][j] * sc + sh);
        }
    }
}

// ---------------- persistent scan kernel ----------------
// 64 blocks x 512 threads (8 waves). Block owns 16 h-columns. Wave w: mq=w&3
// (16 batch rows), kq=w>>2 (k-half). Uz/Uh fragments live in registers/AGPRs
// across all 256 steps. Grid barrier = per-block release flag (own 64B slot)
// + wave-0 parallel poll of all 64 flags + one acquire fence.

__global__ __launch_bounds__(512, 2) void k_scan(const bf16* __restrict__ uzuh,
                                                 const bf16* __restrict__ bnz,
                                                 const bf16* __restrict__ bnh,
                                                 bf16* __restrict__ hb0,
                                                 bf16* __restrict__ hb1,
                                                 float* __restrict__ out,
                                                 unsigned* __restrict__ flags) {
    int tid = threadIdx.x;
    int lane = tid & 63, w = tid >> 6;
    int mq = w & 3, kq = w >> 2;
    int r15 = lane & 15, kseg = lane >> 4;
    int h0 = blockIdx.x * 16;
    int hcol = h0 + r15;

    // permanent B fragments (Uz & Uh rows = this block's h cols, this wave's k-half)
    bf16x8 bZ[16], bH[16];
    {
        const bf16* bzbase = uzuh + (size_t)hcol * H_DIM + kq * 512 + kseg * 8;
        const bf16* bhbase = bzbase + (size_t)H_DIM * H_DIM;
#pragma unroll
        for (int i = 0; i < 16; ++i) {
            bZ[i] = *reinterpret_cast<const bf16x8*>(bzbase + i * 32);
            bH[i] = *reinterpret_cast<const bf16x8*>(bhbase + i * 32);
        }
    }

    __shared__ float red[2][4][64][4];  // [Z|H][mq][lane][j] partials from kq==1

    f32x4 hreg = {};                    // fp32 h carried in regs (kq==0 waves)
    int arow = mq * 16 + r15;
    int bb = mq * 16 + kseg * 4;

    // prefetch step-0 BN'd projections
    float bzv[4], bhv[4];
    if (kq == 0) {
        const bf16* pz = bnz + (size_t)bb * H_DIM + hcol;
        const bf16* ph = bnh + (size_t)bb * H_DIM + hcol;
#pragma unroll
        for (int j = 0; j < 4; ++j) {
            bzv[j] = __bfloat162float(pz[j * H_DIM]);
            bhv[j] = __bfloat162float(ph[j * H_DIM]);
        }
    }

    for (int t = 0; t < T_DIM; ++t) {
        const bf16* hbc = (t & 1) ? hb1 : hb0;
        bf16* hbn = (t & 1) ? hb0 : hb1;

        // k-half GEMM: acc += h_prev[mq rows, kq half] x {Uz,Uh}
        f32x4 accZ = {}, accH = {};
        const bf16* ap = hbc + (size_t)arow * H_DIM + kq * 512 + kseg * 8;
#pragma unroll
        for (int i = 0; i < 16; ++i) {
            bf16x8 a = *reinterpret_cast<const bf16x8*>(ap + i * 32);
            accZ = __builtin_amdgcn_mfma_f32_16x16x32_bf16(a, bZ[i], accZ, 0, 0, 0);
            accH = __builtin_amdgcn_mfma_f32_16x16x32_bf16(a, bH[i], accH, 0, 0, 0);
        }

        if (kq == 1) {
            *reinterpret_cast<f32x4*>(&red[0][mq][lane][0]) = accZ;
            *reinterpret_cast<f32x4*>(&red[1][mq][lane][0]) = accH;
        }
        __syncthreads();

        if (kq == 0) {
            accZ += *reinterpret_cast<const f32x4*>(&red[0][mq][lane][0]);
            accH += *reinterpret_cast<const f32x4*>(&red[1][mq][lane][0]);
            float* op = out + (size_t)t * (B_DIM * H_DIM);
#pragma unroll
            for (int j = 0; j < 4; ++j) {
                float z = 1.f / (1.f + expf(-(bzv[j] + accZ[j])));
                float hu = fmaxf(bhv[j] + accH[j], 0.f);
                float hn = z * hreg[j] + (1.f - z) * hu;
                hreg[j] = hn;
                size_t idx = (size_t)(bb + j) * H_DIM + hcol;
                op[idx] = hn;
                hbn[idx] = __float2bfloat16(hn);
                if (t == T_DIM - 1)
                    out[(size_t)T_DIM * (B_DIM * H_DIM) + idx] = hn;  // h_final
            }
            // prefetch next step's BN'd projections (hides under barrier spin)
            if (t + 1 < T_DIM) {
                const bf16* pz = bnz + (size_t)(t + 1) * (B_DIM * H_DIM) + (size_t)bb * H_DIM + hcol;
                const bf16* ph = bnh + (size_t)(t + 1) * (B_DIM * H_DIM) + (size_t)bb * H_DIM + hcol;
#pragma unroll
                for (int j = 0; j < 4; ++j) {
                    bzv[j] = __bfloat162float(pz[j * H_DIM]);
                    bhv[j] = __bfloat162float(ph[j * H_DIM]);
                }
            }
        }

        if (t < T_DIM - 1) {
            __syncthreads();   // all waves done: LDS reads finished, h stores issued
            if (w == 0) {
                if (lane == 0)
                    __hip_atomic_store(&flags[(size_t)blockIdx.x * 16], (unsigned)(t + 1),
                                       __ATOMIC_RELEASE, __HIP_MEMORY_SCOPE_AGENT);
                unsigned v;
                do {
                    v = __hip_atomic_load(&flags[(size_t)lane * 16],
                                          __ATOMIC_RELAXED, __HIP_MEMORY_SCOPE_AGENT);
                    if (!__any(v <= (unsigned)t)) break;
                    __builtin_amdgcn_s_sleep(1);
                } while (true);
                __builtin_amdgcn_fence(__ATOMIC_ACQUIRE, "agent");
            }
            __syncthreads();
        }
    }
}

// ---------------- workspace layout (bytes) ----------------
#define OFF_XB    ((size_t)0)                     // 16 MB  bf16 x
#define OFF_WZX   ((size_t)16777216)              // 1 MB
#define OFF_WHX   ((size_t)17825792)              // 8 MB
#define OFF_UZUH  ((size_t)26214400)              // 4 MB
#define OFF_WDIAG ((size_t)30408704)              // 32 KB
#define OFF_BNZ   ((size_t)30441472)              // 32 MB
#define OFF_BNH   ((size_t)63995904)              // 32 MB
#define OFF_BAR   ((size_t)97550336)              // 4 KB flag array
#define OFF_HB0   ((size_t)98074624)              // 128 KB
#define OFF_HB1   ((size_t)98205696)              // 128 KB

extern "C" void kernel_launch(void* const* d_in, const int* in_sizes, int n_in,
                              void* d_out, int out_size, void* d_ws, size_t ws_size,
                              hipStream_t stream) {
    const float* x      = (const float*)d_in[0];
    const float* Wzx    = (const float*)d_in[1];
    const float* Whx    = (const float*)d_in[2];
    const float* Uz     = (const float*)d_in[3];
    const float* Uh     = (const float*)d_in[4];
    const float* b_unit = (const float*)d_in[5];
    const float* Wh_in  = (const float*)d_in[6];
    const float* gz     = (const float*)d_in[7];
    const float* bz     = (const float*)d_in[8];
    const float* gh     = (const float*)d_in[9];
    const float* bh     = (const float*)d_in[10];
    const float* mask   = (const float*)d_in[11];

    char* ws = (char*)d_ws;
    bf16*     xb    = (bf16*)(ws + OFF_XB);
    bf16*     wzx_b = (bf16*)(ws + OFF_WZX);
    bf16*     whx_b = (bf16*)(ws + OFF_WHX);
    bf16*     uzuh  = (bf16*)(ws + OFF_UZUH);
    float*    wdiag = (float*)(ws + OFF_WDIAG);
    bf16*     bnz   = (bf16*)(ws + OFF_BNZ);
    bf16*     bnh   = (bf16*)(ws + OFF_BNH);
    unsigned* flags = (unsigned*)(ws + OFF_BAR);
    bf16*     hb0   = (bf16*)(ws + OFF_HB0);
    bf16*     hb1   = (bf16*)(ws + OFF_HB1);

    float* out = (float*)d_out;

    // 1. convert inputs to bf16 (vectorized)
    k_cvt4<<<2048, 256, 0, stream>>>(x, (u16*)xb, T_DIM * B_DIM * I_DIM / 4);
    k_cvt4<<<512, 256, 0, stream>>>(Wzx, (u16*)wzx_b, H_DIM * I_DIM / 4);
    k_cvt4<<<2048, 256, 0, stream>>>(Whx, (u16*)whx_b, U_DIM * H_DIM * I_DIM / 4);
    k_pack_uzuh<<<2048, 256, 0, stream>>>(Uz, Uh, (u16*)uzuh);
    k_wdiag<<<(H_DIM * U_DIM + 255) / 256, 256, 0, stream>>>(Wh_in, mask, wdiag);

    // 2. fused GEMM+BN -> bnz, bnh (bf16)
    {
        dim3 gz_grid(H_DIM / 64, T_DIM);
        k_gemm_zx<<<gz_grid, 256, 0, stream>>>(xb, wzx_b, gz, bz, bnz);
        dim3 gs_grid(H_DIM / 16, T_DIM);
        k_gemm_s<<<gs_grid, 256, 0, stream>>>(xb, whx_b, b_unit, wdiag, gh, bh, bnh);
    }

    // 3. init h = 0 and flags = 0
    hipMemsetAsync(hb0, 0, (size_t)B_DIM * H_DIM * sizeof(bf16), stream);
    hipMemsetAsync(flags, 0, 4096, stream);

    // 4. persistent scan: one kernel, distributed-flag grid barrier per step
    k_scan<<<NBLK, 512, 0, stream>>>(uzuh, bnz, bnh, hb0, hb1, out, flags);
}